// Round 11
// baseline (267.577 us; speedup 1.0000x reference)
//
#include <hip/hip_runtime.h>
#include <cstdint>
#include <cstddef>

// ---------- types ----------
typedef __attribute__((ext_vector_type(8))) __bf16 bf16x8;   // MFMA A/B frag (4 VGPRs)
typedef __attribute__((ext_vector_type(4))) float  f32x4;    // MFMA C/D frag

__device__ __forceinline__ unsigned short f32_to_bf16(float f) {
    union { float f; unsigned int u; } cv;
    cv.f = f;
    unsigned int u = cv.u;
    return (unsigned short)((u + 0x7fffu + ((u >> 16) & 1u)) >> 16);  // RNE
}

__device__ __forceinline__ float bf16_to_f32(unsigned short h) {
    union { unsigned int u; float f; } cv;
    cv.u = ((unsigned int)h) << 16;
    return cv.f;
}

// async global->LDS, 16 bytes per lane. LDS dest is wave-uniform base + lane*16.
__device__ __forceinline__ void async_copy16(const unsigned short* g, unsigned short* lds) {
    __builtin_amdgcn_global_load_lds(
        (const __attribute__((address_space(1))) unsigned int*)g,
        (__attribute__((address_space(3))) unsigned int*)lds,
        16, 0, 0);
}

// ---------- fused fp32 -> bf16 cast for all five inputs + lsum zeroing (R7) ----------
__global__ __launch_bounds__(256) void cast_all(
    const float* __restrict__ x,  const float* __restrict__ y,
    const float* __restrict__ wq, const float* __restrict__ wk, const float* __restrict__ wv,
    unsigned short* __restrict__ xb,  unsigned short* __restrict__ yb,
    unsigned short* __restrict__ wqb, unsigned short* __restrict__ wkb,
    unsigned short* __restrict__ wvb, float* __restrict__ lsum)
{
    int b = blockIdx.x;
    if (b >= 11264) {   // last block: zero lsum[4096]
        float4 z = {0.f, 0.f, 0.f, 0.f};
#pragma unroll
        for (int t = 0; t < 4; ++t)
            ((float4*)lsum)[threadIdx.x * 4 + t] = z;
        return;
    }
    const float* s; unsigned short* d; int base;
    if      (b < 4096)  { s = x;  d = xb;  base = b; }
    else if (b < 8192)  { s = y;  d = yb;  base = b - 4096; }
    else if (b < 9216)  { s = wq; d = wqb; base = b - 8192; }
    else if (b < 10240) { s = wk; d = wkb; base = b - 9216; }
    else                { s = wv; d = wvb; base = b - 10240; }
    int i = base * 256 + threadIdx.x;
    float4 v = ((const float4*)s)[i];
    ushort4 o;
    o.x = f32_to_bf16(v.x);
    o.y = f32_to_bf16(v.y);
    o.z = f32_to_bf16(v.z);
    o.w = f32_to_bf16(v.w);
    ((ushort4*)d)[i] = o;
}

// ---------- prefetch double-buffered GEMM core, BK=32 (R4/R7 proven) ----------
__device__ __forceinline__ void gemm_core_pf(
    const unsigned short* __restrict__ A, const unsigned short* __restrict__ B,
    int K, int rowBase, int colBase, int kBeg, int kEnd,
    unsigned short* ldsA, unsigned short* ldsB, f32x4 acc[4][4])
{
    const int tid  = threadIdx.x;
    const int lane = tid & 63;
    const int wave = tid >> 6;
    const int quad = lane >> 4;
    const int r    = lane & 15;
    const int wm   = wave >> 1;
    const int wn   = wave & 1;

    const int c1 = tid + 256;
    const long aOff0 = (long)(rowBase + (tid >> 2)) * K + (tid & 3) * 8;
    const long aOff1 = (long)(rowBase + (c1  >> 2)) * K + (c1  & 3) * 8;
    const long bOff0 = (long)(colBase + (tid >> 2)) * K + (tid & 3) * 8;
    const long bOff1 = (long)(colBase + (c1  >> 2)) * K + (c1  & 3) * 8;
    unsigned short* ldsA0 = ldsA + tid * 8;
    unsigned short* ldsA1 = ldsA + c1 * 8;
    unsigned short* ldsB0 = ldsB + tid * 8;
    unsigned short* ldsB1 = ldsB + c1 * 8;

    const int aReadOff = (wm * 64 + r) * 32 + quad * 8;
    const int bReadOff = (wn * 64 + r) * 32 + quad * 8;

    const int nSteps = (kEnd - kBeg) >> 5;

    async_copy16(A + aOff0 + kBeg, ldsA0);
    async_copy16(A + aOff1 + kBeg, ldsA1);
    async_copy16(B + bOff0 + kBeg, ldsB0);
    async_copy16(B + bOff1 + kBeg, ldsB1);

    for (int s = 0; s < nSteps; ++s) {
        const int cur = (s & 1) << 12;          // 0 or 4096 elems
        const int nxt = cur ^ 4096;
        __builtin_amdgcn_s_waitcnt(0);          // tile s arrived
        __syncthreads();                        // visible to all; buf[nxt] free
        if (s + 1 < nSteps) {
            const int kn = kBeg + ((s + 1) << 5);
            async_copy16(A + aOff0 + kn, ldsA0 + nxt);
            async_copy16(A + aOff1 + kn, ldsA1 + nxt);
            async_copy16(B + bOff0 + kn, ldsB0 + nxt);
            async_copy16(B + bOff1 + kn, ldsB1 + nxt);
        }
        bf16x8 af[4], bfr[4];
#pragma unroll
        for (int i = 0; i < 4; ++i)
            af[i] = *(const bf16x8*)(ldsA + cur + aReadOff + i * 16 * 32);
#pragma unroll
        for (int j = 0; j < 4; ++j)
            bfr[j] = *(const bf16x8*)(ldsB + cur + bReadOff + j * 16 * 32);
#pragma unroll
        for (int i = 0; i < 4; ++i)
#pragma unroll
            for (int j = 0; j < 4; ++j)
                acc[i][j] = __builtin_amdgcn_mfma_f32_16x16x32_bf16(af[i], bfr[j], acc[i][j], 0, 0, 0);
    }
}

// ---------- batched projections: 768 blocks (3 problems x 256), K=1024 (R7) ----------
__global__ __launch_bounds__(256, 2)
void proj_batched(const unsigned short* __restrict__ xb, const unsigned short* __restrict__ yb,
                  const unsigned short* __restrict__ wqb, const unsigned short* __restrict__ wkb,
                  const unsigned short* __restrict__ wvb,
                  unsigned short* __restrict__ q, unsigned short* __restrict__ k,
                  unsigned short* __restrict__ vt,
                  const float* __restrict__ bq, const float* __restrict__ bk,
                  const float* __restrict__ bv)
{
    __shared__ __align__(16) unsigned short ldsA[2 * 128 * 32];
    __shared__ __align__(16) unsigned short ldsB[2 * 128 * 32];

    const int b = blockIdx.x;
    const int z = b >> 8;
    const int rb = b & 255;

    const unsigned short *A, *B;
    unsigned short* C;
    const float* bias;
    int N, rowBase, colBase;
    bool biasPerRow;
    if (z == 0) {
        A = xb; B = wqb; C = q; bias = bq; N = 1024; biasPerRow = false;
        colBase = (rb >> 5) * 128; rowBase = (rb & 31) * 128;   // bid%8 = rowTile%8
    } else if (z == 1) {
        A = yb; B = wkb; C = k; bias = bk; N = 1024; biasPerRow = false;
        colBase = (rb >> 5) * 128; rowBase = (rb & 31) * 128;
    } else {
        A = wvb; B = yb; C = vt; bias = bv; N = 4096; biasPerRow = true;
        colBase = (rb >> 3) * 128; rowBase = (rb & 7) * 128;    // bid%8 = rowTile
    }

    f32x4 acc[4][4];
#pragma unroll
    for (int i = 0; i < 4; ++i)
#pragma unroll
        for (int j = 0; j < 4; ++j)
            acc[i][j] = (f32x4){0.f, 0.f, 0.f, 0.f};

    gemm_core_pf(A, B, 1024, rowBase, colBase, 0, 1024, ldsA, ldsB, acc);

    const int lane = threadIdx.x & 63;
    const int wave = threadIdx.x >> 6;
    const int quad = lane >> 4;
    const int r    = lane & 15;
    const int orow0 = rowBase + (wave >> 1) * 64 + quad * 4;
    const int ocol0 = colBase + (wave & 1) * 64 + r;

#pragma unroll
    for (int i = 0; i < 4; ++i)
#pragma unroll
        for (int e = 0; e < 4; ++e) {
            const int row = orow0 + i * 16 + e;
            const float brow = biasPerRow ? bias[row] : 0.f;
#pragma unroll
            for (int j = 0; j < 4; ++j) {
                const int col = ocol0 + j * 16;
                const float bb = biasPerRow ? brow : bias[col];
                C[(long)row * N + col] = f32_to_bf16(acc[i][j][e] + bb);
            }
        }
}

// ---------- scores, B-direct core: P = exp2(scale2 * (q @ k^T)) bf16, lsum atomics ----
// LDS-bandwidth diet: A (q-tile) staged via global_load_lds as before, but B (k)
// fragments are loaded DIRECTLY global->VGPR (per lane 16 contiguous bytes; per wave
// 16 rows x 64 B full cachelines, L2-resident). B-frags for step s+1 prefetched right
// after the barrier -> a full compute phase to fly; retired by the next step's
// vmcnt(0). LDS traffic/step: 48 KB -> 24 KB (below the 310-cyc MFMA pipe demand).
__global__ __launch_bounds__(256, 2)
void scores_gemm_bd(const unsigned short* __restrict__ q, const unsigned short* __restrict__ k,
                    unsigned short* __restrict__ P, float* __restrict__ lsum, float scale2)
{
    __shared__ __align__(16) unsigned short ldsA[2 * 128 * 32];

    const int tid  = threadIdx.x;
    const int lane = tid & 63;
    const int wave = tid >> 6;
    const int quad = lane >> 4;
    const int r    = lane & 15;
    const int wm   = wave >> 1;
    const int wn   = wave & 1;

    const int rowBase = blockIdx.y * 128;
    const int colBase = blockIdx.x * 128;

    // A staging (identical to gemm_core_pf)
    const int c1 = tid + 256;
    const long aOff0 = (long)(rowBase + (tid >> 2)) * 1024 + (tid & 3) * 8;
    const long aOff1 = (long)(rowBase + (c1  >> 2)) * 1024 + (c1  & 3) * 8;
    unsigned short* ldsA0 = ldsA + tid * 8;
    unsigned short* ldsA1 = ldsA + c1 * 8;
    const int aReadOff = (wm * 64 + r) * 32 + quad * 8;

    // B direct: lane's fragment row for col-block j is (colBase + wn*64 + j*16 + r),
    // k-offset quad*8. 16-byte aligned (row*2048 + quad*16 bytes).
    const unsigned short* Brow[4];
#pragma unroll
    for (int j = 0; j < 4; ++j)
        Brow[j] = k + (long)(colBase + wn * 64 + j * 16 + r) * 1024 + quad * 8;

    f32x4 acc[4][4];
#pragma unroll
    for (int i = 0; i < 4; ++i)
#pragma unroll
        for (int j = 0; j < 4; ++j)
            acc[i][j] = (f32x4){0.f, 0.f, 0.f, 0.f};

    // prologue: A tile 0 -> buf0; B frags for step 0 -> regs
    async_copy16(q + aOff0, ldsA0);
    async_copy16(q + aOff1, ldsA1);
    bf16x8 bnxt[4];
#pragma unroll
    for (int j = 0; j < 4; ++j)
        bnxt[j] = *(const bf16x8*)(Brow[j]);

    for (int s = 0; s < 32; ++s) {
        const int cur = (s & 1) << 12;
        const int nxt = cur ^ 4096;
        __builtin_amdgcn_s_waitcnt(0);          // A tile s in LDS, B frags s in regs
        __syncthreads();
        bf16x8 bcur[4];
#pragma unroll
        for (int j = 0; j < 4; ++j) bcur[j] = bnxt[j];
        if (s + 1 < 32) {
            const int kn = (s + 1) * 32;
            async_copy16(q + aOff0 + kn, ldsA0 + nxt);
            async_copy16(q + aOff1 + kn, ldsA1 + nxt);
#pragma unroll
            for (int j = 0; j < 4; ++j)
                bnxt[j] = *(const bf16x8*)(Brow[j] + kn);
        }
        bf16x8 af[4];
#pragma unroll
        for (int i = 0; i < 4; ++i)
            af[i] = *(const bf16x8*)(ldsA + cur + aReadOff + i * 16 * 32);
#pragma unroll
        for (int i = 0; i < 4; ++i)
#pragma unroll
            for (int j = 0; j < 4; ++j)
                acc[i][j] = __builtin_amdgcn_mfma_f32_16x16x32_bf16(af[i], bcur[j], acc[i][j], 0, 0, 0);
    }

    const int orow0 = rowBase + wm * 64 + quad * 4;
    const int ocol0 = colBase + wn * 64 + r;

#pragma unroll
    for (int i = 0; i < 4; ++i)
#pragma unroll
        for (int e = 0; e < 4; ++e) {
            const int row = orow0 + i * 16 + e;
            float rs = 0.f;
#pragma unroll
            for (int j = 0; j < 4; ++j) {
                const int col = ocol0 + j * 16;
                const float p = exp2f(acc[i][j][e] * scale2);
                rs += p;
                P[(long)row * 4096 + col] = f32_to_bf16(p);
            }
#pragma unroll
            for (int m = 1; m < 16; m <<= 1) rs += __shfl_xor(rs, m, 64);
            if (r == 0) atomicAdd(&lsum[row], rs);
        }
}

// ---------- output GEMM, split-K x4 (R7) ----------
template <int ATOMIC>
__global__ __launch_bounds__(256, 2)
void out_gemm_splitk(const unsigned short* __restrict__ P, const unsigned short* __restrict__ vt,
                     void* __restrict__ Out)
{
    __shared__ __align__(16) unsigned short ldsA[2 * 128 * 32];
    __shared__ __align__(16) unsigned short ldsB[2 * 128 * 32];

    const int bid = blockIdx.x;
    const int xt  = bid >> 7;          // 0..7  (output col tile)
    const int yz  = bid & 127;
    const int yt  = yz >> 2;           // 0..31 (output row tile)
    const int zt  = yz & 3;            // 0..3  (k split)

    const int rowBase = yt * 128;
    const int colBase = xt * 128;
    const int kBeg = zt * 1024;

    f32x4 acc[4][4];
#pragma unroll
    for (int i = 0; i < 4; ++i)
#pragma unroll
        for (int j = 0; j < 4; ++j)
            acc[i][j] = (f32x4){0.f, 0.f, 0.f, 0.f};

    gemm_core_pf(P, vt, 4096, rowBase, colBase, kBeg, kBeg + 1024, ldsA, ldsB, acc);

    const int lane = threadIdx.x & 63;
    const int wave = threadIdx.x >> 6;
    const int quad = lane >> 4;
    const int r    = lane & 15;
    const int orow0 = rowBase + (wave >> 1) * 64 + quad * 4;
    const int ocol0 = colBase + (wave & 1) * 64 + r;

#pragma unroll
    for (int i = 0; i < 4; ++i)
#pragma unroll
        for (int e = 0; e < 4; ++e) {
            const int row = orow0 + i * 16 + e;
#pragma unroll
            for (int j = 0; j < 4; ++j) {
                const int col = ocol0 + j * 16;
                if (ATOMIC) {
                    atomicAdd(&((float*)Out)[(long)row * 1024 + col], acc[i][j][e]);
                } else {
                    unsigned short* parts = (unsigned short*)Out + (size_t)zt * (4096 * 1024);
                    parts[(long)row * 1024 + col] = f32_to_bf16(acc[i][j][e]);
                }
            }
        }
}

// ---------- reduce 4 bf16 partials + normalize (R7) ----------
__global__ __launch_bounds__(256) void reduce_norm(const unsigned short* __restrict__ parts,
                                                   const float* __restrict__ lsum,
                                                   float* __restrict__ O) {
    const int i = blockIdx.x * 256 + threadIdx.x;   // ushort4/float4 group index; 256 per row
    const float inv = 1.0f / lsum[i >> 8];
    const size_t stride = (size_t)(4096 * 1024) / 4;   // ushort4 units
    ushort4 a = ((const ushort4*)parts)[i];
    ushort4 b = ((const ushort4*)parts)[i + stride];
    ushort4 c = ((const ushort4*)parts)[i + 2 * stride];
    ushort4 d = ((const ushort4*)parts)[i + 3 * stride];
    float4 o;
    o.x = (bf16_to_f32(a.x) + bf16_to_f32(b.x) + bf16_to_f32(c.x) + bf16_to_f32(d.x)) * inv;
    o.y = (bf16_to_f32(a.y) + bf16_to_f32(b.y) + bf16_to_f32(c.y) + bf16_to_f32(d.y)) * inv;
    o.z = (bf16_to_f32(a.z) + bf16_to_f32(b.z) + bf16_to_f32(c.z) + bf16_to_f32(d.z)) * inv;
    o.w = (bf16_to_f32(a.w) + bf16_to_f32(b.w) + bf16_to_f32(c.w) + bf16_to_f32(d.w)) * inv;
    ((float4*)O)[i] = o;
}

// ---------- normalize in place (atomic fallback path) ----------
__global__ __launch_bounds__(256) void norm_rows(float* __restrict__ O, const float* __restrict__ lsum) {
    int i = blockIdx.x * 256 + threadIdx.x;
    const float inv = 1.0f / lsum[i >> 8];
    float4 v = ((const float4*)O)[i];
    v.x *= inv; v.y *= inv; v.z *= inv; v.w *= inv;
    ((float4*)O)[i] = v;
}

extern "C" void kernel_launch(void* const* d_in, const int* in_sizes, int n_in,
                              void* d_out, int out_size, void* d_ws, size_t ws_size,
                              hipStream_t stream) {
    const float* x  = (const float*)d_in[0];
    const float* y  = (const float*)d_in[1];
    const float* Wq = (const float*)d_in[2];
    const float* bq = (const float*)d_in[3];
    const float* Wk = (const float*)d_in[4];
    const float* bk = (const float*)d_in[5];
    const float* Wv = (const float*)d_in[6];
    const float* bv = (const float*)d_in[7];

    constexpr int Nx = 4096, Ny = 4096, H = 1024, Dv = 1024, Kin = 1024;

    char* ws = (char*)d_ws;
    size_t off = 0;
    auto carve = [&](size_t bytes) {
        char* p = ws + off;
        off += (bytes + 255) & ~(size_t)255;
        return p;
    };

    unsigned short* q_bf  = (unsigned short*)carve((size_t)Nx * H * 2);   // 8 MB
    unsigned short* k_bf  = (unsigned short*)carve((size_t)Ny * H * 2);   // 8 MB
    unsigned short* vt_bf = (unsigned short*)carve((size_t)Dv * Ny * 2);  // 8 MB
    float*          lsum  = (float*)carve((size_t)Nx * sizeof(float));    // 16 KB

    // overlay: phase 1 = bf16 casts (22 MB), phase 2 = P (32 MB)
    char* overlay = ws + off;
    unsigned short* x_bf  = (unsigned short*)overlay;
    unsigned short* y_bf  = x_bf  + (size_t)Nx * Kin;
    unsigned short* Wq_bf = y_bf  + (size_t)Ny * Kin;
    unsigned short* Wk_bf = Wq_bf + (size_t)H  * Kin;
    unsigned short* Wv_bf = Wk_bf + (size_t)H  * Kin;
    unsigned short* P_bf  = (unsigned short*)overlay;  // [Nx, Ny] bf16, phase 2

    // bf16 partials after the P region: 4 x 8 MB
    const size_t overlay_bytes = (size_t)Nx * Ny * 2;                 // 32 MB
    unsigned short* parts = (unsigned short*)(overlay + overlay_bytes);
    const size_t need_parts = (overlay + overlay_bytes + 4 * (size_t)Nx * Dv * 2) - ws;
    const bool useParts = ws_size >= need_parts;

    if (!useParts)
        hipMemsetAsync(d_out, 0, (size_t)Nx * Dv * sizeof(float), stream);

    // phase 0: all casts + lsum zeroing, one launch
    cast_all<<<11265, 256, 0, stream>>>(x, y, Wq, Wk, Wv, x_bf, y_bf, Wq_bf, Wk_bf, Wv_bf, lsum);

    // phase 1: all three projections, one launch (768 blocks)
    proj_batched<<<768, 256, 0, stream>>>(x_bf, y_bf, Wq_bf, Wk_bf, Wv_bf,
                                          q_bf, k_bf, vt_bf, bq, bk, bv);

    // phase 2a: P = exp(q k^T / 32), lsum row sums (1024 blocks, B-direct core)
    const float scale2 = 1.4426950408889634f / 32.0f;  // log2(e)/sqrt(H)
    scores_gemm_bd<<<dim3(Ny / 128, Nx / 128), 256, 0, stream>>>(q_bf, k_bf, P_bf, lsum, scale2);

    // phase 2b: split-K x4, bf16 partials (1024 blocks, XCD-swizzled)
    if (useParts) {
        out_gemm_splitk<0><<<1024, 256, 0, stream>>>(P_bf, vt_bf, parts);
        reduce_norm<<<Nx * Dv / 4 / 256, 256, 0, stream>>>(parts, lsum, (float*)d_out);
    } else {
        out_gemm_splitk<1><<<1024, 256, 0, stream>>>(P_bf, vt_bf, d_out);
        norm_rows<<<Nx * Dv / 4 / 256, 256, 0, stream>>>((float*)d_out, lsum);
    }
}

// Round 12
// 238.132 us; speedup vs baseline: 1.1236x; 1.1236x over previous
//
#include <hip/hip_runtime.h>
#include <cstdint>
#include <cstddef>

// ---------- types ----------
typedef __attribute__((ext_vector_type(8))) __bf16 bf16x8;   // MFMA A/B frag (4 VGPRs)
typedef __attribute__((ext_vector_type(4))) float  f32x4;    // MFMA C/D frag

__device__ __forceinline__ unsigned short f32_to_bf16(float f) {
    union { float f; unsigned int u; } cv;
    cv.f = f;
    unsigned int u = cv.u;
    return (unsigned short)((u + 0x7fffu + ((u >> 16) & 1u)) >> 16);  // RNE
}

__device__ __forceinline__ float bf16_to_f32(unsigned short h) {
    union { unsigned int u; float f; } cv;
    cv.u = ((unsigned int)h) << 16;
    return cv.f;
}

// async global->LDS, 16 bytes per lane. LDS dest is wave-uniform base + lane*16.
__device__ __forceinline__ void async_copy16(const unsigned short* g, unsigned short* lds) {
    __builtin_amdgcn_global_load_lds(
        (const __attribute__((address_space(1))) unsigned int*)g,
        (__attribute__((address_space(3))) unsigned int*)lds,
        16, 0, 0);
}

// ---------- fused fp32 -> bf16 cast for all five inputs + lsum zeroing (R7) ----------
__global__ __launch_bounds__(256) void cast_all(
    const float* __restrict__ x,  const float* __restrict__ y,
    const float* __restrict__ wq, const float* __restrict__ wk, const float* __restrict__ wv,
    unsigned short* __restrict__ xb,  unsigned short* __restrict__ yb,
    unsigned short* __restrict__ wqb, unsigned short* __restrict__ wkb,
    unsigned short* __restrict__ wvb, float* __restrict__ lsum)
{
    int b = blockIdx.x;
    if (b >= 11264) {   // last block: zero lsum[4096]
        float4 z = {0.f, 0.f, 0.f, 0.f};
#pragma unroll
        for (int t = 0; t < 4; ++t)
            ((float4*)lsum)[threadIdx.x * 4 + t] = z;
        return;
    }
    const float* s; unsigned short* d; int base;
    if      (b < 4096)  { s = x;  d = xb;  base = b; }
    else if (b < 8192)  { s = y;  d = yb;  base = b - 4096; }
    else if (b < 9216)  { s = wq; d = wqb; base = b - 8192; }
    else if (b < 10240) { s = wk; d = wkb; base = b - 9216; }
    else                { s = wv; d = wvb; base = b - 10240; }
    int i = base * 256 + threadIdx.x;
    float4 v = ((const float4*)s)[i];
    ushort4 o;
    o.x = f32_to_bf16(v.x);
    o.y = f32_to_bf16(v.y);
    o.z = f32_to_bf16(v.z);
    o.w = f32_to_bf16(v.w);
    ((ushort4*)d)[i] = o;
}

// ---------- prefetch double-buffered GEMM core, BK=32 (R4/R7 proven) ----------
// acc += A[rowBase:+128, kBeg:kEnd] @ B[colBase:+128, kBeg:kEnd]^T
// Tile s+1 issued into buf^1 BEFORE computing tile s; one barrier per step.
// NOTE (R11): do NOT replace global_load_lds with per-lane direct loads — its
// forced lane-contiguity (64 lanes -> one 1KB segment) is what keeps the TA/TD
// pipe efficient. B-direct register loads regressed 53->88 us.
__device__ __forceinline__ void gemm_core_pf(
    const unsigned short* __restrict__ A, const unsigned short* __restrict__ B,
    int K, int rowBase, int colBase, int kBeg, int kEnd,
    unsigned short* ldsA, unsigned short* ldsB, f32x4 acc[4][4])
{
    const int tid  = threadIdx.x;
    const int lane = tid & 63;
    const int wave = tid >> 6;
    const int quad = lane >> 4;
    const int r    = lane & 15;
    const int wm   = wave >> 1;
    const int wn   = wave & 1;

    const int c1 = tid + 256;
    const long aOff0 = (long)(rowBase + (tid >> 2)) * K + (tid & 3) * 8;
    const long aOff1 = (long)(rowBase + (c1  >> 2)) * K + (c1  & 3) * 8;
    const long bOff0 = (long)(colBase + (tid >> 2)) * K + (tid & 3) * 8;
    const long bOff1 = (long)(colBase + (c1  >> 2)) * K + (c1  & 3) * 8;
    unsigned short* ldsA0 = ldsA + tid * 8;
    unsigned short* ldsA1 = ldsA + c1 * 8;
    unsigned short* ldsB0 = ldsB + tid * 8;
    unsigned short* ldsB1 = ldsB + c1 * 8;

    const int aReadOff = (wm * 64 + r) * 32 + quad * 8;
    const int bReadOff = (wn * 64 + r) * 32 + quad * 8;

    const int nSteps = (kEnd - kBeg) >> 5;

    async_copy16(A + aOff0 + kBeg, ldsA0);
    async_copy16(A + aOff1 + kBeg, ldsA1);
    async_copy16(B + bOff0 + kBeg, ldsB0);
    async_copy16(B + bOff1 + kBeg, ldsB1);

    for (int s = 0; s < nSteps; ++s) {
        const int cur = (s & 1) << 12;          // 0 or 4096 elems
        const int nxt = cur ^ 4096;
        __builtin_amdgcn_s_waitcnt(0);          // tile s arrived
        __syncthreads();                        // visible to all; buf[nxt] free
        if (s + 1 < nSteps) {
            const int kn = kBeg + ((s + 1) << 5);
            async_copy16(A + aOff0 + kn, ldsA0 + nxt);
            async_copy16(A + aOff1 + kn, ldsA1 + nxt);
            async_copy16(B + bOff0 + kn, ldsB0 + nxt);
            async_copy16(B + bOff1 + kn, ldsB1 + nxt);
        }
        bf16x8 af[4], bfr[4];
#pragma unroll
        for (int i = 0; i < 4; ++i)
            af[i] = *(const bf16x8*)(ldsA + cur + aReadOff + i * 16 * 32);
#pragma unroll
        for (int j = 0; j < 4; ++j)
            bfr[j] = *(const bf16x8*)(ldsB + cur + bReadOff + j * 16 * 32);
#pragma unroll
        for (int i = 0; i < 4; ++i)
#pragma unroll
            for (int j = 0; j < 4; ++j)
                acc[i][j] = __builtin_amdgcn_mfma_f32_16x16x32_bf16(af[i], bfr[j], acc[i][j], 0, 0, 0);
    }
}

// ---------- batched projections: 768 blocks (3 problems x 256), K=1024 (R7) ----------
__global__ __launch_bounds__(256, 2)
void proj_batched(const unsigned short* __restrict__ xb, const unsigned short* __restrict__ yb,
                  const unsigned short* __restrict__ wqb, const unsigned short* __restrict__ wkb,
                  const unsigned short* __restrict__ wvb,
                  unsigned short* __restrict__ q, unsigned short* __restrict__ k,
                  unsigned short* __restrict__ vt,
                  const float* __restrict__ bq, const float* __restrict__ bk,
                  const float* __restrict__ bv)
{
    __shared__ __align__(16) unsigned short ldsA[2 * 128 * 32];
    __shared__ __align__(16) unsigned short ldsB[2 * 128 * 32];

    const int b = blockIdx.x;
    const int z = b >> 8;
    const int rb = b & 255;

    const unsigned short *A, *B;
    unsigned short* C;
    const float* bias;
    int N, rowBase, colBase;
    bool biasPerRow;
    if (z == 0) {
        A = xb; B = wqb; C = q; bias = bq; N = 1024; biasPerRow = false;
        colBase = (rb >> 5) * 128; rowBase = (rb & 31) * 128;   // bid%8 = rowTile%8
    } else if (z == 1) {
        A = yb; B = wkb; C = k; bias = bk; N = 1024; biasPerRow = false;
        colBase = (rb >> 5) * 128; rowBase = (rb & 31) * 128;
    } else {
        A = wvb; B = yb; C = vt; bias = bv; N = 4096; biasPerRow = true;
        colBase = (rb >> 3) * 128; rowBase = (rb & 7) * 128;    // bid%8 = rowTile
    }

    f32x4 acc[4][4];
#pragma unroll
    for (int i = 0; i < 4; ++i)
#pragma unroll
        for (int j = 0; j < 4; ++j)
            acc[i][j] = (f32x4){0.f, 0.f, 0.f, 0.f};

    gemm_core_pf(A, B, 1024, rowBase, colBase, 0, 1024, ldsA, ldsB, acc);

    const int lane = threadIdx.x & 63;
    const int wave = threadIdx.x >> 6;
    const int quad = lane >> 4;
    const int r    = lane & 15;
    const int orow0 = rowBase + (wave >> 1) * 64 + quad * 4;
    const int ocol0 = colBase + (wave & 1) * 64 + r;

#pragma unroll
    for (int i = 0; i < 4; ++i)
#pragma unroll
        for (int e = 0; e < 4; ++e) {
            const int row = orow0 + i * 16 + e;
            const float brow = biasPerRow ? bias[row] : 0.f;
#pragma unroll
            for (int j = 0; j < 4; ++j) {
                const int col = ocol0 + j * 16;
                const float bb = biasPerRow ? brow : bias[col];
                C[(long)row * N + col] = f32_to_bf16(acc[i][j][e] + bb);
            }
        }
}

// ---------- scores: P = exp2(scale2 * (q @ k^T)) bf16, lsum[row] += rowsum (R7) ----------
__global__ __launch_bounds__(256, 2)
void scores_gemm(const unsigned short* __restrict__ q, const unsigned short* __restrict__ k,
                 unsigned short* __restrict__ P, float* __restrict__ lsum, float scale2)
{
    __shared__ __align__(16) unsigned short ldsA[2 * 128 * 32];
    __shared__ __align__(16) unsigned short ldsB[2 * 128 * 32];

    const int rowBase = blockIdx.y * 128;
    const int colBase = blockIdx.x * 128;

    f32x4 acc[4][4];
#pragma unroll
    for (int i = 0; i < 4; ++i)
#pragma unroll
        for (int j = 0; j < 4; ++j)
            acc[i][j] = (f32x4){0.f, 0.f, 0.f, 0.f};

    gemm_core_pf(q, k, 1024, rowBase, colBase, 0, 1024, ldsA, ldsB, acc);

    const int lane = threadIdx.x & 63;
    const int wave = threadIdx.x >> 6;
    const int quad = lane >> 4;
    const int r    = lane & 15;
    const int orow0 = rowBase + (wave >> 1) * 64 + quad * 4;
    const int ocol0 = colBase + (wave & 1) * 64 + r;

#pragma unroll
    for (int i = 0; i < 4; ++i)
#pragma unroll
        for (int e = 0; e < 4; ++e) {
            const int row = orow0 + i * 16 + e;
            float rs = 0.f;
#pragma unroll
            for (int j = 0; j < 4; ++j) {
                const int col = ocol0 + j * 16;
                const float p = exp2f(acc[i][j][e] * scale2);
                rs += p;
                P[(long)row * 4096 + col] = f32_to_bf16(p);
            }
#pragma unroll
            for (int m = 1; m < 16; m <<= 1) rs += __shfl_xor(rs, m, 64);
            if (r == 0) atomicAdd(&lsum[row], rs);
        }
}

// ---------- output GEMM, split-K x2 (64 steps/block: 2x better amortization) ----------
// 1D grid 512: bid = x*64 + y*2 + z -> bid%8 invariant in x (P row-strip sharing per XCD).
// ATOMIC=0: store bf16 partial z into parts + z*8MB (plain coalesced stores).
// ATOMIC=1: fp32 atomicAdd into O (fallback when ws too small).
template <int ATOMIC>
__global__ __launch_bounds__(256, 2)
void out_gemm_splitk(const unsigned short* __restrict__ P, const unsigned short* __restrict__ vt,
                     void* __restrict__ Out)
{
    __shared__ __align__(16) unsigned short ldsA[2 * 128 * 32];
    __shared__ __align__(16) unsigned short ldsB[2 * 128 * 32];

    const int bid = blockIdx.x;
    const int xt  = bid >> 6;          // 0..7  (output col tile)
    const int yz  = bid & 63;
    const int yt  = yz >> 1;           // 0..31 (output row tile)
    const int zt  = yz & 1;            // 0..1  (k split)

    const int rowBase = yt * 128;
    const int colBase = xt * 128;
    const int kBeg = zt * 2048;

    f32x4 acc[4][4];
#pragma unroll
    for (int i = 0; i < 4; ++i)
#pragma unroll
        for (int j = 0; j < 4; ++j)
            acc[i][j] = (f32x4){0.f, 0.f, 0.f, 0.f};

    gemm_core_pf(P, vt, 4096, rowBase, colBase, kBeg, kBeg + 2048, ldsA, ldsB, acc);

    const int lane = threadIdx.x & 63;
    const int wave = threadIdx.x >> 6;
    const int quad = lane >> 4;
    const int r    = lane & 15;
    const int orow0 = rowBase + (wave >> 1) * 64 + quad * 4;
    const int ocol0 = colBase + (wave & 1) * 64 + r;

#pragma unroll
    for (int i = 0; i < 4; ++i)
#pragma unroll
        for (int e = 0; e < 4; ++e) {
            const int row = orow0 + i * 16 + e;
#pragma unroll
            for (int j = 0; j < 4; ++j) {
                const int col = ocol0 + j * 16;
                if (ATOMIC) {
                    atomicAdd(&((float*)Out)[(long)row * 1024 + col], acc[i][j][e]);
                } else {
                    unsigned short* parts = (unsigned short*)Out + (size_t)zt * (4096 * 1024);
                    parts[(long)row * 1024 + col] = f32_to_bf16(acc[i][j][e]);
                }
            }
        }
}

// ---------- reduce 2 bf16 partials + normalize: O = (P0+P1) / lsum[row] ----------
__global__ __launch_bounds__(256) void reduce_norm(const unsigned short* __restrict__ parts,
                                                   const float* __restrict__ lsum,
                                                   float* __restrict__ O) {
    const int i = blockIdx.x * 256 + threadIdx.x;   // ushort4/float4 group index; 256 per row
    const float inv = 1.0f / lsum[i >> 8];
    const size_t stride = (size_t)(4096 * 1024) / 4;   // ushort4 units
    ushort4 a = ((const ushort4*)parts)[i];
    ushort4 b = ((const ushort4*)parts)[i + stride];
    float4 o;
    o.x = (bf16_to_f32(a.x) + bf16_to_f32(b.x)) * inv;
    o.y = (bf16_to_f32(a.y) + bf16_to_f32(b.y)) * inv;
    o.z = (bf16_to_f32(a.z) + bf16_to_f32(b.z)) * inv;
    o.w = (bf16_to_f32(a.w) + bf16_to_f32(b.w)) * inv;
    ((float4*)O)[i] = o;
}

// ---------- normalize in place (atomic fallback path) ----------
__global__ __launch_bounds__(256) void norm_rows(float* __restrict__ O, const float* __restrict__ lsum) {
    int i = blockIdx.x * 256 + threadIdx.x;
    const float inv = 1.0f / lsum[i >> 8];
    float4 v = ((const float4*)O)[i];
    v.x *= inv; v.y *= inv; v.z *= inv; v.w *= inv;
    ((float4*)O)[i] = v;
}

extern "C" void kernel_launch(void* const* d_in, const int* in_sizes, int n_in,
                              void* d_out, int out_size, void* d_ws, size_t ws_size,
                              hipStream_t stream) {
    const float* x  = (const float*)d_in[0];
    const float* y  = (const float*)d_in[1];
    const float* Wq = (const float*)d_in[2];
    const float* bq = (const float*)d_in[3];
    const float* Wk = (const float*)d_in[4];
    const float* bk = (const float*)d_in[5];
    const float* Wv = (const float*)d_in[6];
    const float* bv = (const float*)d_in[7];

    constexpr int Nx = 4096, Ny = 4096, H = 1024, Dv = 1024, Kin = 1024;

    char* ws = (char*)d_ws;
    size_t off = 0;
    auto carve = [&](size_t bytes) {
        char* p = ws + off;
        off += (bytes + 255) & ~(size_t)255;
        return p;
    };

    unsigned short* q_bf  = (unsigned short*)carve((size_t)Nx * H * 2);   // 8 MB
    unsigned short* k_bf  = (unsigned short*)carve((size_t)Ny * H * 2);   // 8 MB
    unsigned short* vt_bf = (unsigned short*)carve((size_t)Dv * Ny * 2);  // 8 MB
    float*          lsum  = (float*)carve((size_t)Nx * sizeof(float));    // 16 KB

    // overlay: phase 1 = bf16 casts (22 MB), phase 2 = P (32 MB)
    char* overlay = ws + off;
    unsigned short* x_bf  = (unsigned short*)overlay;
    unsigned short* y_bf  = x_bf  + (size_t)Nx * Kin;
    unsigned short* Wq_bf = y_bf  + (size_t)Ny * Kin;
    unsigned short* Wk_bf = Wq_bf + (size_t)H  * Kin;
    unsigned short* Wv_bf = Wk_bf + (size_t)H  * Kin;
    unsigned short* P_bf  = (unsigned short*)overlay;  // [Nx, Ny] bf16, phase 2

    // bf16 partials after the P region: 2 x 8 MB
    const size_t overlay_bytes = (size_t)Nx * Ny * 2;                 // 32 MB
    unsigned short* parts = (unsigned short*)(overlay + overlay_bytes);
    const size_t need_parts = (overlay + overlay_bytes + 2 * (size_t)Nx * Dv * 2) - ws;
    const bool useParts = ws_size >= need_parts;

    if (!useParts)
        hipMemsetAsync(d_out, 0, (size_t)Nx * Dv * sizeof(float), stream);

    // phase 0: all casts + lsum zeroing, one launch
    cast_all<<<11265, 256, 0, stream>>>(x, y, Wq, Wk, Wv, x_bf, y_bf, Wq_bf, Wk_bf, Wv_bf, lsum);

    // phase 1: all three projections, one launch (768 blocks)
    proj_batched<<<768, 256, 0, stream>>>(x_bf, y_bf, Wq_bf, Wk_bf, Wv_bf,
                                          q_bf, k_bf, vt_bf, bq, bk, bv);

    // phase 2a: P = exp(q k^T / 32), lsum row sums (1024 blocks)
    const float scale2 = 1.4426950408889634f / 32.0f;  // log2(e)/sqrt(H)
    scores_gemm<<<dim3(Ny / 128, Nx / 128), 256, 0, stream>>>(q_bf, k_bf, P_bf, lsum, scale2);

    // phase 2b: split-K x2, bf16 partials (512 blocks, 64 steps each, XCD-swizzled)
    if (useParts) {
        out_gemm_splitk<0><<<512, 256, 0, stream>>>(P_bf, vt_bf, parts);
        reduce_norm<<<Nx * Dv / 4 / 256, 256, 0, stream>>>(parts, lsum, (float*)d_out);
    } else {
        out_gemm_splitk<1><<<512, 256, 0, stream>>>(P_bf, vt_bf, d_out);
        norm_rows<<<Nx * Dv / 4 / 256, 256, 0, stream>>>((float*)d_out, lsum);
    }
}

// Round 13
// 236.460 us; speedup vs baseline: 1.1316x; 1.0071x over previous
//
#include <hip/hip_runtime.h>
#include <cstdint>
#include <cstddef>

// ---------- types ----------
typedef __attribute__((ext_vector_type(8))) __bf16 bf16x8;   // MFMA A/B frag (4 VGPRs)
typedef __attribute__((ext_vector_type(4))) float  f32x4;    // MFMA C/D frag

// s_waitcnt simm16 (gfx9/CDNA): [3:0] vmcnt lo, [6:4] expcnt, [11:8] lgkmcnt, [15:14] vmcnt hi
#define WAITCNT_VM(n) ((n & 0xF) | 0x70 | 0xF00 | (((n) >> 4) << 14))   // wait vmcnt<=n only

__device__ __forceinline__ unsigned short f32_to_bf16(float f) {
    union { float f; unsigned int u; } cv;
    cv.f = f;
    unsigned int u = cv.u;
    return (unsigned short)((u + 0x7fffu + ((u >> 16) & 1u)) >> 16);  // RNE
}

__device__ __forceinline__ float bf16_to_f32(unsigned short h) {
    union { unsigned int u; float f; } cv;
    cv.u = ((unsigned int)h) << 16;
    return cv.f;
}

// async global->LDS, 16 bytes per lane. LDS dest is wave-uniform base + lane*16.
__device__ __forceinline__ void async_copy16(const unsigned short* g, unsigned short* lds) {
    __builtin_amdgcn_global_load_lds(
        (const __attribute__((address_space(1))) unsigned int*)g,
        (__attribute__((address_space(3))) unsigned int*)lds,
        16, 0, 0);
}

// ---------- fused fp32 -> bf16 cast for all five inputs + lsum zeroing (R7) ----------
__global__ __launch_bounds__(256) void cast_all(
    const float* __restrict__ x,  const float* __restrict__ y,
    const float* __restrict__ wq, const float* __restrict__ wk, const float* __restrict__ wv,
    unsigned short* __restrict__ xb,  unsigned short* __restrict__ yb,
    unsigned short* __restrict__ wqb, unsigned short* __restrict__ wkb,
    unsigned short* __restrict__ wvb, float* __restrict__ lsum)
{
    int b = blockIdx.x;
    if (b >= 11264) {   // last block: zero lsum[4096]
        float4 z = {0.f, 0.f, 0.f, 0.f};
#pragma unroll
        for (int t = 0; t < 4; ++t)
            ((float4*)lsum)[threadIdx.x * 4 + t] = z;
        return;
    }
    const float* s; unsigned short* d; int base;
    if      (b < 4096)  { s = x;  d = xb;  base = b; }
    else if (b < 8192)  { s = y;  d = yb;  base = b - 4096; }
    else if (b < 9216)  { s = wq; d = wqb; base = b - 8192; }
    else if (b < 10240) { s = wk; d = wkb; base = b - 9216; }
    else                { s = wv; d = wvb; base = b - 10240; }
    int i = base * 256 + threadIdx.x;
    float4 v = ((const float4*)s)[i];
    ushort4 o;
    o.x = f32_to_bf16(v.x);
    o.y = f32_to_bf16(v.y);
    o.z = f32_to_bf16(v.z);
    o.w = f32_to_bf16(v.w);
    ((ushort4*)d)[i] = o;
}

// ---------- 1-deep prefetch GEMM core, BK=32 (R4/R7 proven; used at 3-4 blocks/CU) ----------
// NOTE (R11): keep global_load_lds — its forced lane-contiguity (64 lanes -> one 1KB
// segment) is what keeps the TA/TD pipe efficient. Direct per-lane loads regressed 53->88.
__device__ __forceinline__ void gemm_core_pf(
    const unsigned short* __restrict__ A, const unsigned short* __restrict__ B,
    int K, int rowBase, int colBase, int kBeg, int kEnd,
    unsigned short* ldsA, unsigned short* ldsB, f32x4 acc[4][4])
{
    const int tid  = threadIdx.x;
    const int lane = tid & 63;
    const int wave = tid >> 6;
    const int quad = lane >> 4;
    const int r    = lane & 15;
    const int wm   = wave >> 1;
    const int wn   = wave & 1;

    const int c1 = tid + 256;
    const long aOff0 = (long)(rowBase + (tid >> 2)) * K + (tid & 3) * 8;
    const long aOff1 = (long)(rowBase + (c1  >> 2)) * K + (c1  & 3) * 8;
    const long bOff0 = (long)(colBase + (tid >> 2)) * K + (tid & 3) * 8;
    const long bOff1 = (long)(colBase + (c1  >> 2)) * K + (c1  & 3) * 8;
    unsigned short* ldsA0 = ldsA + tid * 8;
    unsigned short* ldsA1 = ldsA + c1 * 8;
    unsigned short* ldsB0 = ldsB + tid * 8;
    unsigned short* ldsB1 = ldsB + c1 * 8;

    const int aReadOff = (wm * 64 + r) * 32 + quad * 8;
    const int bReadOff = (wn * 64 + r) * 32 + quad * 8;

    const int nSteps = (kEnd - kBeg) >> 5;

    async_copy16(A + aOff0 + kBeg, ldsA0);
    async_copy16(A + aOff1 + kBeg, ldsA1);
    async_copy16(B + bOff0 + kBeg, ldsB0);
    async_copy16(B + bOff1 + kBeg, ldsB1);

    for (int s = 0; s < nSteps; ++s) {
        const int cur = (s & 1) << 12;          // 0 or 4096 elems
        const int nxt = cur ^ 4096;
        __builtin_amdgcn_s_waitcnt(0);          // tile s arrived
        __syncthreads();                        // visible to all; buf[nxt] free
        if (s + 1 < nSteps) {
            const int kn = kBeg + ((s + 1) << 5);
            async_copy16(A + aOff0 + kn, ldsA0 + nxt);
            async_copy16(A + aOff1 + kn, ldsA1 + nxt);
            async_copy16(B + bOff0 + kn, ldsB0 + nxt);
            async_copy16(B + bOff1 + kn, ldsB1 + nxt);
        }
        bf16x8 af[4], bfr[4];
#pragma unroll
        for (int i = 0; i < 4; ++i)
            af[i] = *(const bf16x8*)(ldsA + cur + aReadOff + i * 16 * 32);
#pragma unroll
        for (int j = 0; j < 4; ++j)
            bfr[j] = *(const bf16x8*)(ldsB + cur + bReadOff + j * 16 * 32);
#pragma unroll
        for (int i = 0; i < 4; ++i)
#pragma unroll
            for (int j = 0; j < 4; ++j)
                acc[i][j] = __builtin_amdgcn_mfma_f32_16x16x32_bf16(af[i], bfr[j], acc[i][j], 0, 0, 0);
    }
}

// ---------- 2-deep prefetch GEMM core, BK=32, 3 LDS buffers (R5-verified) ----------
// For kernels whose grid caps residency at <=2 blocks/CU (48 KB LDS is then free).
// Tiles s and s+1 always in flight; vmcnt(4) retires tile s only; raw s_barrier
// (no compiler vmcnt(0) drain) + one sched_barrier to pin the wait/barrier order.
__device__ __forceinline__ void gemm_core_pf2(
    const unsigned short* __restrict__ A, const unsigned short* __restrict__ B,
    int K, int rowBase, int colBase, int kBeg, int kEnd,
    unsigned short* ldsA, unsigned short* ldsB, f32x4 acc[4][4])
{
    const int tid  = threadIdx.x;
    const int lane = tid & 63;
    const int wave = tid >> 6;
    const int quad = lane >> 4;
    const int r    = lane & 15;
    const int wm   = wave >> 1;
    const int wn   = wave & 1;

    const int c1 = tid + 256;
    const long aOff0 = (long)(rowBase + (tid >> 2)) * K + (tid & 3) * 8;
    const long aOff1 = (long)(rowBase + (c1  >> 2)) * K + (c1  & 3) * 8;
    const long bOff0 = (long)(colBase + (tid >> 2)) * K + (tid & 3) * 8;
    const long bOff1 = (long)(colBase + (c1  >> 2)) * K + (c1  & 3) * 8;
    unsigned short* ldsA0 = ldsA + tid * 8;
    unsigned short* ldsA1 = ldsA + c1 * 8;
    unsigned short* ldsB0 = ldsB + tid * 8;
    unsigned short* ldsB1 = ldsB + c1 * 8;

    const int aReadOff = (wm * 64 + r) * 32 + quad * 8;
    const int bReadOff = (wn * 64 + r) * 32 + quad * 8;

    const int nSteps = (kEnd - kBeg) >> 5;

    // prologue: tile 0 -> buf0, tile 1 -> buf1
    async_copy16(A + aOff0 + kBeg, ldsA0);
    async_copy16(A + aOff1 + kBeg, ldsA1);
    async_copy16(B + bOff0 + kBeg, ldsB0);
    async_copy16(B + bOff1 + kBeg, ldsB1);
    if (nSteps > 1) {
        async_copy16(A + aOff0 + kBeg + 32, ldsA0 + 4096);
        async_copy16(A + aOff1 + kBeg + 32, ldsA1 + 4096);
        async_copy16(B + bOff0 + kBeg + 32, ldsB0 + 4096);
        async_copy16(B + bOff1 + kBeg + 32, ldsB1 + 4096);
    }

    int cur = 0;            // LDS buffer (elems offset / 4096) holding tile s
    for (int s = 0; s < nSteps; ++s) {
        if (s + 1 < nSteps) __builtin_amdgcn_s_waitcnt(WAITCNT_VM(4));
        else                __builtin_amdgcn_s_waitcnt(WAITCNT_VM(0));
        __builtin_amdgcn_s_barrier();
        __builtin_amdgcn_sched_barrier(0);   // keep wait+barrier ahead of the reads below
        if (s + 2 < nSteps) {
            int nb = cur + 2; if (nb >= 3) nb -= 3;          // (s+2)%3
            const int no = nb * 4096;
            const int kn = kBeg + ((s + 2) << 5);
            async_copy16(A + aOff0 + kn, ldsA0 + no);
            async_copy16(A + aOff1 + kn, ldsA1 + no);
            async_copy16(B + bOff0 + kn, ldsB0 + no);
            async_copy16(B + bOff1 + kn, ldsB1 + no);
        }
        const int co = cur * 4096;
        bf16x8 af[4], bfr[4];
#pragma unroll
        for (int i = 0; i < 4; ++i)
            af[i] = *(const bf16x8*)(ldsA + co + aReadOff + i * 16 * 32);
#pragma unroll
        for (int j = 0; j < 4; ++j)
            bfr[j] = *(const bf16x8*)(ldsB + co + bReadOff + j * 16 * 32);
#pragma unroll
        for (int i = 0; i < 4; ++i)
#pragma unroll
            for (int j = 0; j < 4; ++j)
                acc[i][j] = __builtin_amdgcn_mfma_f32_16x16x32_bf16(af[i], bfr[j], acc[i][j], 0, 0, 0);
        if (++cur == 3) cur = 0;
    }
}

// ---------- batched projections: 768 blocks (3 problems x 256), K=1024 (R7) ----------
__global__ __launch_bounds__(256, 2)
void proj_batched(const unsigned short* __restrict__ xb, const unsigned short* __restrict__ yb,
                  const unsigned short* __restrict__ wqb, const unsigned short* __restrict__ wkb,
                  const unsigned short* __restrict__ wvb,
                  unsigned short* __restrict__ q, unsigned short* __restrict__ k,
                  unsigned short* __restrict__ vt,
                  const float* __restrict__ bq, const float* __restrict__ bk,
                  const float* __restrict__ bv)
{
    __shared__ __align__(16) unsigned short ldsA[2 * 128 * 32];
    __shared__ __align__(16) unsigned short ldsB[2 * 128 * 32];

    const int b = blockIdx.x;
    const int z = b >> 8;
    const int rb = b & 255;

    const unsigned short *A, *B;
    unsigned short* C;
    const float* bias;
    int N, rowBase, colBase;
    bool biasPerRow;
    if (z == 0) {
        A = xb; B = wqb; C = q; bias = bq; N = 1024; biasPerRow = false;
        colBase = (rb >> 5) * 128; rowBase = (rb & 31) * 128;   // bid%8 = rowTile%8
    } else if (z == 1) {
        A = yb; B = wkb; C = k; bias = bk; N = 1024; biasPerRow = false;
        colBase = (rb >> 5) * 128; rowBase = (rb & 31) * 128;
    } else {
        A = wvb; B = yb; C = vt; bias = bv; N = 4096; biasPerRow = true;
        colBase = (rb >> 3) * 128; rowBase = (rb & 7) * 128;    // bid%8 = rowTile
    }

    f32x4 acc[4][4];
#pragma unroll
    for (int i = 0; i < 4; ++i)
#pragma unroll
        for (int j = 0; j < 4; ++j)
            acc[i][j] = (f32x4){0.f, 0.f, 0.f, 0.f};

    gemm_core_pf(A, B, 1024, rowBase, colBase, 0, 1024, ldsA, ldsB, acc);

    const int lane = threadIdx.x & 63;
    const int wave = threadIdx.x >> 6;
    const int quad = lane >> 4;
    const int r    = lane & 15;
    const int orow0 = rowBase + (wave >> 1) * 64 + quad * 4;
    const int ocol0 = colBase + (wave & 1) * 64 + r;

#pragma unroll
    for (int i = 0; i < 4; ++i)
#pragma unroll
        for (int e = 0; e < 4; ++e) {
            const int row = orow0 + i * 16 + e;
            const float brow = biasPerRow ? bias[row] : 0.f;
#pragma unroll
            for (int j = 0; j < 4; ++j) {
                const int col = ocol0 + j * 16;
                const float bb = biasPerRow ? brow : bias[col];
                C[(long)row * N + col] = f32_to_bf16(acc[i][j][e] + bb);
            }
        }
}

// ---------- scores: P = exp2(scale2 * (q @ k^T)) bf16, lsum[row] += rowsum (R7) ----------
__global__ __launch_bounds__(256, 2)
void scores_gemm(const unsigned short* __restrict__ q, const unsigned short* __restrict__ k,
                 unsigned short* __restrict__ P, float* __restrict__ lsum, float scale2)
{
    __shared__ __align__(16) unsigned short ldsA[2 * 128 * 32];
    __shared__ __align__(16) unsigned short ldsB[2 * 128 * 32];

    const int rowBase = blockIdx.y * 128;
    const int colBase = blockIdx.x * 128;

    f32x4 acc[4][4];
#pragma unroll
    for (int i = 0; i < 4; ++i)
#pragma unroll
        for (int j = 0; j < 4; ++j)
            acc[i][j] = (f32x4){0.f, 0.f, 0.f, 0.f};

    gemm_core_pf(q, k, 1024, rowBase, colBase, 0, 1024, ldsA, ldsB, acc);

    const int lane = threadIdx.x & 63;
    const int wave = threadIdx.x >> 6;
    const int quad = lane >> 4;
    const int r    = lane & 15;
    const int orow0 = rowBase + (wave >> 1) * 64 + quad * 4;
    const int ocol0 = colBase + (wave & 1) * 64 + r;

#pragma unroll
    for (int i = 0; i < 4; ++i)
#pragma unroll
        for (int e = 0; e < 4; ++e) {
            const int row = orow0 + i * 16 + e;
            float rs = 0.f;
#pragma unroll
            for (int j = 0; j < 4; ++j) {
                const int col = ocol0 + j * 16;
                const float p = exp2f(acc[i][j][e] * scale2);
                rs += p;
                P[(long)row * 4096 + col] = f32_to_bf16(p);
            }
#pragma unroll
            for (int m = 1; m < 16; m <<= 1) rs += __shfl_xor(rs, m, 64);
            if (r == 0) atomicAdd(&lsum[row], rs);
        }
}

// ---------- output GEMM, split-K x2, 2-deep pipelined core ----------
// 512 blocks = 2 blocks/CU by grid alone -> 48 KB LDS and VGPR 72 are free here;
// the 2-deep pipeline attacks the thin-TLP latency exposure (R5 decomposition).
// 1D grid 512: bid = x*64 + y*2 + z -> bid%8 invariant in x (P row-strip per XCD).
template <int ATOMIC>
__global__ __launch_bounds__(256, 2)
void out_gemm_splitk(const unsigned short* __restrict__ P, const unsigned short* __restrict__ vt,
                     void* __restrict__ Out)
{
    __shared__ __align__(16) unsigned short ldsA[3 * 128 * 32];
    __shared__ __align__(16) unsigned short ldsB[3 * 128 * 32];

    const int bid = blockIdx.x;
    const int xt  = bid >> 6;          // 0..7  (output col tile)
    const int yz  = bid & 63;
    const int yt  = yz >> 1;           // 0..31 (output row tile)
    const int zt  = yz & 1;            // 0..1  (k split)

    const int rowBase = yt * 128;
    const int colBase = xt * 128;
    const int kBeg = zt * 2048;

    f32x4 acc[4][4];
#pragma unroll
    for (int i = 0; i < 4; ++i)
#pragma unroll
        for (int j = 0; j < 4; ++j)
            acc[i][j] = (f32x4){0.f, 0.f, 0.f, 0.f};

    gemm_core_pf2(P, vt, 4096, rowBase, colBase, kBeg, kBeg + 2048, ldsA, ldsB, acc);

    const int lane = threadIdx.x & 63;
    const int wave = threadIdx.x >> 6;
    const int quad = lane >> 4;
    const int r    = lane & 15;
    const int orow0 = rowBase + (wave >> 1) * 64 + quad * 4;
    const int ocol0 = colBase + (wave & 1) * 64 + r;

#pragma unroll
    for (int i = 0; i < 4; ++i)
#pragma unroll
        for (int e = 0; e < 4; ++e) {
            const int row = orow0 + i * 16 + e;
#pragma unroll
            for (int j = 0; j < 4; ++j) {
                const int col = ocol0 + j * 16;
                if (ATOMIC) {
                    atomicAdd(&((float*)Out)[(long)row * 1024 + col], acc[i][j][e]);
                } else {
                    unsigned short* parts = (unsigned short*)Out + (size_t)zt * (4096 * 1024);
                    parts[(long)row * 1024 + col] = f32_to_bf16(acc[i][j][e]);
                }
            }
        }
}

// ---------- reduce 2 bf16 partials + normalize: O = (P0+P1) / lsum[row] ----------
__global__ __launch_bounds__(256) void reduce_norm(const unsigned short* __restrict__ parts,
                                                   const float* __restrict__ lsum,
                                                   float* __restrict__ O) {
    const int i = blockIdx.x * 256 + threadIdx.x;   // ushort4/float4 group index; 256 per row
    const float inv = 1.0f / lsum[i >> 8];
    const size_t stride = (size_t)(4096 * 1024) / 4;   // ushort4 units
    ushort4 a = ((const ushort4*)parts)[i];
    ushort4 b = ((const ushort4*)parts)[i + stride];
    float4 o;
    o.x = (bf16_to_f32(a.x) + bf16_to_f32(b.x)) * inv;
    o.y = (bf16_to_f32(a.y) + bf16_to_f32(b.y)) * inv;
    o.z = (bf16_to_f32(a.z) + bf16_to_f32(b.z)) * inv;
    o.w = (bf16_to_f32(a.w) + bf16_to_f32(b.w)) * inv;
    ((float4*)O)[i] = o;
}

// ---------- normalize in place (atomic fallback path) ----------
__global__ __launch_bounds__(256) void norm_rows(float* __restrict__ O, const float* __restrict__ lsum) {
    int i = blockIdx.x * 256 + threadIdx.x;
    const float inv = 1.0f / lsum[i >> 8];
    float4 v = ((const float4*)O)[i];
    v.x *= inv; v.y *= inv; v.z *= inv; v.w *= inv;
    ((float4*)O)[i] = v;
}

extern "C" void kernel_launch(void* const* d_in, const int* in_sizes, int n_in,
                              void* d_out, int out_size, void* d_ws, size_t ws_size,
                              hipStream_t stream) {
    const float* x  = (const float*)d_in[0];
    const float* y  = (const float*)d_in[1];
    const float* Wq = (const float*)d_in[2];
    const float* bq = (const float*)d_in[3];
    const float* Wk = (const float*)d_in[4];
    const float* bk = (const float*)d_in[5];
    const float* Wv = (const float*)d_in[6];
    const float* bv = (const float*)d_in[7];

    constexpr int Nx = 4096, Ny = 4096, H = 1024, Dv = 1024, Kin = 1024;

    char* ws = (char*)d_ws;
    size_t off = 0;
    auto carve = [&](size_t bytes) {
        char* p = ws + off;
        off += (bytes + 255) & ~(size_t)255;
        return p;
    };

    unsigned short* q_bf  = (unsigned short*)carve((size_t)Nx * H * 2);   // 8 MB
    unsigned short* k_bf  = (unsigned short*)carve((size_t)Ny * H * 2);   // 8 MB
    unsigned short* vt_bf = (unsigned short*)carve((size_t)Dv * Ny * 2);  // 8 MB
    float*          lsum  = (float*)carve((size_t)Nx * sizeof(float));    // 16 KB

    // overlay: phase 1 = bf16 casts (22 MB), phase 2 = P (32 MB)
    char* overlay = ws + off;
    unsigned short* x_bf  = (unsigned short*)overlay;
    unsigned short* y_bf  = x_bf  + (size_t)Nx * Kin;
    unsigned short* Wq_bf = y_bf  + (size_t)Ny * Kin;
    unsigned short* Wk_bf = Wq_bf + (size_t)H  * Kin;
    unsigned short* Wv_bf = Wk_bf + (size_t)H  * Kin;
    unsigned short* P_bf  = (unsigned short*)overlay;  // [Nx, Ny] bf16, phase 2

    // bf16 partials after the P region: 2 x 8 MB
    const size_t overlay_bytes = (size_t)Nx * Ny * 2;                 // 32 MB
    unsigned short* parts = (unsigned short*)(overlay + overlay_bytes);
    const size_t need_parts = (overlay + overlay_bytes + 2 * (size_t)Nx * Dv * 2) - ws;
    const bool useParts = ws_size >= need_parts;

    if (!useParts)
        hipMemsetAsync(d_out, 0, (size_t)Nx * Dv * sizeof(float), stream);

    // phase 0: all casts + lsum zeroing, one launch
    cast_all<<<11265, 256, 0, stream>>>(x, y, Wq, Wk, Wv, x_bf, y_bf, Wq_bf, Wk_bf, Wv_bf, lsum);

    // phase 1: all three projections, one launch (768 blocks)
    proj_batched<<<768, 256, 0, stream>>>(x_bf, y_bf, Wq_bf, Wk_bf, Wv_bf,
                                          q_bf, k_bf, vt_bf, bq, bk, bv);

    // phase 2a: P = exp(q k^T / 32), lsum row sums (1024 blocks)
    const float scale2 = 1.4426950408889634f / 32.0f;  // log2(e)/sqrt(H)
    scores_gemm<<<dim3(Ny / 128, Nx / 128), 256, 0, stream>>>(q_bf, k_bf, P_bf, lsum, scale2);

    // phase 2b: split-K x2, 2-deep core, bf16 partials (512 blocks, XCD-swizzled)
    if (useParts) {
        out_gemm_splitk<0><<<512, 256, 0, stream>>>(P_bf, vt_bf, parts);
        reduce_norm<<<Nx * Dv / 4 / 256, 256, 0, stream>>>(parts, lsum, (float*)d_out);
    } else {
        out_gemm_splitk<1><<<512, 256, 0, stream>>>(P_bf, vt_bf, d_out);
        norm_rows<<<Nx * Dv / 4 / 256, 256, 0, stream>>>((float*)d_out, lsum);
    }
}